// Round 5
// baseline (690.533 us; speedup 1.0000x reference)
//
#include <hip/hip_runtime.h>
#include <math.h>
#include <stdint.h>

#define BATCH 16
#define RDIM 2048
#define UDIM 2048
#define DDIM 1024

typedef __attribute__((ext_vector_type(8))) short short8;
typedef __attribute__((ext_vector_type(4))) float f32x4;
typedef __attribute__((ext_vector_type(8))) unsigned short ushort8;
typedef __attribute__((ext_vector_type(4))) unsigned short ushort4v;
typedef __attribute__((ext_vector_type(4))) float float4v;

__device__ __forceinline__ float bf2f(unsigned short u) {
  unsigned int x = ((unsigned int)u) << 16;
  return __builtin_bit_cast(float, x);
}
__device__ __forceinline__ unsigned short f2bf(float f) {
  unsigned int x = __builtin_bit_cast(unsigned int, f);
  unsigned int r = (x + 0x7fffu + ((x >> 16) & 1u)) >> 16;
  return (unsigned short)r;
}

__device__ __forceinline__ void gload_lds16(const void* g, void* l) {
  __builtin_amdgcn_global_load_lds(
      (const __attribute__((address_space(1))) void*)(uintptr_t)g,
      (__attribute__((address_space(3))) void*)(uint32_t)(uintptr_t)l,
      16, 0, 0);
}

#define FENCE() __builtin_amdgcn_sched_barrier(0)
#define BAR() __builtin_amdgcn_s_barrier()
#define LGKM0() asm volatile("s_waitcnt lgkmcnt(0)" ::: "memory")
#define VMCNT8() asm volatile("s_waitcnt vmcnt(8)" ::: "memory")

// ---------------- conversions ----------------

__global__ __launch_bounds__(256) void k_conv_bf16(const float* __restrict__ in,
                                                   unsigned short* __restrict__ out,
                                                   float scale) {
  const long i = ((long)blockIdx.x * 256 + threadIdx.x) * 8;
  float4v a = *(const float4v*)(in + i);
  float4v b = *(const float4v*)(in + i + 4);
  ushort8 o;
#pragma unroll
  for (int j = 0; j < 4; ++j) o[j] = f2bf(a[j] * scale);
#pragma unroll
  for (int j = 0; j < 4; ++j) o[4 + j] = f2bf(b[j] * scale);
  *(ushort8*)(out + i) = o;
}

// out[c*rows + r] = bf16(in[r*cols + c])
__global__ void k_transpose_bf16(const float* __restrict__ in,
                                 unsigned short* __restrict__ out,
                                 int rows, int cols, long sIn, long sOut) {
  __shared__ unsigned short tile[64][65];
  const long bz = blockIdx.z;
  in += bz * sIn;
  out += bz * sOut;
  const int r0 = blockIdx.x * 64;
  const int c0 = blockIdx.y * 64;
  const int tx = threadIdx.x;  // 64
  const int ty = threadIdx.y;  // 4
#pragma unroll
  for (int i = 0; i < 16; ++i) {
    const int r = ty + i * 4;
    tile[r][tx] = f2bf(in[(long)(r0 + r) * cols + c0 + tx]);
  }
  __syncthreads();
#pragma unroll
  for (int i = 0; i < 16; ++i) {
    const int r = ty + i * 4;
    out[(long)(c0 + r) * rows + r0 + tx] = tile[tx][r];
  }
}

// ---------------- GEMM: C[M,N] = A[M,K] * B[N,K]^T, bf16 in, fp32 acc -------
// 256x256 tile, BK=64 split into two k-halves, 512 threads = 8 waves (2Mx4N).
// LDS [buf][A,B][ks][256 rows x 32 elem] = 8 x 16 KiB slots, 64-B rows.
// T2 swizzle: phys 16B-slot = logicalSlot ^ ((row>>1)&3) -> conflict-free
// ds_read_b128; staging keeps LDS dest linear and pre-applies the inverse
// permutation on the global source column (both-sides involution).
// Phase structure (m201 template): per phase
//   {ds_reads; stage; FENCE; BAR; [vmcnt(8)]; lgkm(0); FENCE; setprio1;
//    16 MFMA; setprio0; BAR}
// The BAR between read-issue and lgkm-wait lets all 8 waves' reads drain in
// the LDS unit at full CU bandwidth (vs per-wave serialized), and the second
// BAR makes slot-reuse WAR-safe by construction.
// vmcnt(8) only at p1/p3 (counted, never 0 in main loop). Ledger invariant at
// tile start (oldest first, 2 loads each): {A-k1(t), B-k1(t), A-k0(t+1),
// B-k0(t+1)} = 8 outstanding; each vmcnt(8) lands exactly the 2 half-tiles
// the following phases read.
// T1: bijective XCD remap, y-fastest decode for panel reuse in per-XCD L2.

template <int EPI>
__global__ __launch_bounds__(512, 2) void gemm_bt(
    const unsigned short* __restrict__ A, const unsigned short* __restrict__ B,
    void* __restrict__ Cout, int N, int K, long sA, long sB, long sC,
    const float* __restrict__ bias, const unsigned short* __restrict__ res) {
  __shared__ __align__(128) unsigned short lds[2][2][2][256 * 32];

  // ---- T1: XCD-aware bijective remap (all grids are multiples of 8) ----
  int lin = blockIdx.x + gridDim.x * (blockIdx.y + gridDim.y * blockIdx.z);
  lin = (lin & 7) * ((gridDim.x * gridDim.y * gridDim.z) >> 3) + (lin >> 3);
  const int by = lin % gridDim.y;       // y-fastest: share A-panel in L2
  int rest = lin / gridDim.y;
  const int bx = rest % gridDim.x;
  const int bz = rest / gridDim.x;

  const unsigned short* Ab = A + (long)bz * sA;
  const unsigned short* Bb = B + (long)bz * sB;

  const int tid = threadIdx.x;
  const int w = tid >> 6;
  const int lane = tid & 63;
  const int wm = w >> 2;
  const int wn = w & 3;
  const long rowBase = (long)bx * 256;
  const long colBase = (long)by * 256;

  // staging: lane l writes LDS linear byte w*1024 + q*8192 + l*16
  //   -> row = w*16 + q*128 + (l>>2), physSlot = l&3
  //   -> fetch logical slot (l&3) ^ ((row>>1)&3) = (l&3) ^ ((l>>3)&3)
  const int stRow = w * 16 + (lane >> 2);
  const int stKc = ((lane & 3) ^ ((lane >> 3) & 3)) << 3;  // elements
  const unsigned short* gA = Ab + (rowBase + stRow) * (long)K + stKc;
  const unsigned short* gB = Bb + (colBase + stRow) * (long)K + stKc;
  const long qStep = (long)128 * K;
  char* ldsB = (char*)&lds[0][0][0][0];
  const int dOff = w * 1024;

  auto STAGE = [&](int buf, int op, int ks, int kadd) {
    const unsigned short* g = (op == 0 ? gA : gB) + kadd;
    char* d = ldsB + ((buf * 4 + op * 2 + ks) << 14) + dOff;
    gload_lds16(g, d);
    gload_lds16(g + qStep, d + 8192);
  };

  // fragment reads: row = base16 + laneM, phys slot = laneQ ^ ((laneM>>1)&3)
  const int laneM = lane & 15;
  const int laneQ = lane >> 4;
  const int swz = (laneQ ^ ((laneM >> 1) & 3)) << 4;
  const int rdA = (wm * 128 + laneM) * 64 + swz;
  const int rdB = (wn * 64 + laneM) * 64 + swz;

  f32x4 acc[8][4] = {};
  const int NT = K >> 6;
  const int NTm1 = NT - 1;

  // prologue: A-k0(0) B-k0(0) A-k1(0) B-k1(0) A-k0(1) B-k0(1)
  STAGE(0, 0, 0, 0);
  STAGE(0, 1, 0, 0);
  STAGE(0, 0, 1, 32);
  STAGE(0, 1, 1, 32);
  STAGE(1, 0, 0, 64);
  STAGE(1, 1, 0, 64);
  VMCNT8();  // A-k0(0), B-k0(0) landed
  BAR();
  FENCE();

  for (int t = 0; t < NT; ++t) {
    const int cur = t & 1;
    const int sA0 = (cur * 4 + 0) << 14;
    const int sA1 = (cur * 4 + 1) << 14;
    const int sB0 = (cur * 4 + 2) << 14;
    const int sB1 = (cur * 4 + 3) << 14;
    const int t1 = (t + 1 <= NTm1 ? t + 1 : NTm1);
    const int t2 = (t + 2 <= NTm1 ? t + 2 : NTm1);
    const int k1add = t1 * 64 + 32;
    const int k0add = t2 * 64;

    short8 a0[4], a1[4], b0[4];

    // ---- p0: reads k0 (A rows 0-3, B), stage A-k1(t+1) ----
#pragma unroll
    for (int m = 0; m < 4; ++m)
      a0[m] = *(const short8*)(ldsB + sA0 + rdA + m * 1024);
#pragma unroll
    for (int n = 0; n < 4; ++n)
      b0[n] = *(const short8*)(ldsB + sB0 + rdB + n * 1024);
    STAGE(cur ^ 1, 0, 1, k1add);
    FENCE();
    BAR();
    LGKM0();
    FENCE();
    __builtin_amdgcn_s_setprio(1);
#pragma unroll
    for (int m = 0; m < 4; ++m)
#pragma unroll
      for (int n = 0; n < 4; ++n)
        acc[m][n] = __builtin_amdgcn_mfma_f32_16x16x32_bf16(a0[m], b0[n],
                                                            acc[m][n], 0, 0, 0);
    __builtin_amdgcn_s_setprio(0);
    BAR();

    // ---- p1: reads k0 (A rows 4-7), stage B-k1(t+1), vmcnt ----
#pragma unroll
    for (int m = 0; m < 4; ++m)
      a1[m] = *(const short8*)(ldsB + sA0 + rdA + (4 + m) * 1024);
    STAGE(cur ^ 1, 1, 1, k1add);
    FENCE();
    BAR();
    VMCNT8();  // A-k1(t), B-k1(t) landed (read at p2/p3)
    LGKM0();
    FENCE();
    __builtin_amdgcn_s_setprio(1);
#pragma unroll
    for (int m = 0; m < 4; ++m)
#pragma unroll
      for (int n = 0; n < 4; ++n)
        acc[4 + m][n] = __builtin_amdgcn_mfma_f32_16x16x32_bf16(a1[m], b0[n],
                                                                acc[4 + m][n], 0, 0, 0);
    __builtin_amdgcn_s_setprio(0);
    BAR();

    // ---- p2: reads k1 (A rows 0-3, B), stage A-k0(t+2) ----
#pragma unroll
    for (int m = 0; m < 4; ++m)
      a0[m] = *(const short8*)(ldsB + sA1 + rdA + m * 1024);
#pragma unroll
    for (int n = 0; n < 4; ++n)
      b0[n] = *(const short8*)(ldsB + sB1 + rdB + n * 1024);
    STAGE(cur, 0, 0, k0add);
    FENCE();
    BAR();
    LGKM0();
    FENCE();
    __builtin_amdgcn_s_setprio(1);
#pragma unroll
    for (int m = 0; m < 4; ++m)
#pragma unroll
      for (int n = 0; n < 4; ++n)
        acc[m][n] = __builtin_amdgcn_mfma_f32_16x16x32_bf16(a0[m], b0[n],
                                                            acc[m][n], 0, 0, 0);
    __builtin_amdgcn_s_setprio(0);
    BAR();

    // ---- p3: reads k1 (A rows 4-7), stage B-k0(t+2), vmcnt ----
#pragma unroll
    for (int m = 0; m < 4; ++m)
      a1[m] = *(const short8*)(ldsB + sA1 + rdA + (4 + m) * 1024);
    STAGE(cur, 1, 0, k0add);
    FENCE();
    BAR();
    VMCNT8();  // A-k0(t+1), B-k0(t+1) landed (read at next p0/p1)
    LGKM0();
    FENCE();
    __builtin_amdgcn_s_setprio(1);
#pragma unroll
    for (int m = 0; m < 4; ++m)
#pragma unroll
      for (int n = 0; n < 4; ++n)
        acc[4 + m][n] = __builtin_amdgcn_mfma_f32_16x16x32_bf16(a1[m], b0[n],
                                                                acc[4 + m][n], 0, 0, 0);
    __builtin_amdgcn_s_setprio(0);
    BAR();
  }

  const long r0 = rowBase + wm * 128;
  const long c0 = colBase + wn * 64;
  const int cr = (lane >> 4) << 2;
  const int cc = lane & 15;

  if constexpr (EPI == 0) {
    unsigned short* C = (unsigned short*)Cout + (long)bz * sC;
#pragma unroll
    for (int i = 0; i < 8; ++i)
#pragma unroll
      for (int j = 0; j < 4; ++j)
#pragma unroll
        for (int jj = 0; jj < 4; ++jj)
          C[(r0 + i * 16 + cr + jj) * N + (c0 + j * 16 + cc)] = f2bf(acc[i][j][jj]);
  } else if constexpr (EPI == 1) {
    unsigned short* C = (unsigned short*)Cout;
#pragma unroll
    for (int i = 0; i < 8; ++i)
#pragma unroll
      for (int j = 0; j < 4; ++j)
#pragma unroll
        for (int jj = 0; jj < 4; ++jj) {
          const long col = c0 + j * 16 + cc;
          float v = acc[i][j][jj] + bias[col];
          v = fmaxf(v, 0.f);
          C[(r0 + i * 16 + cr + jj) * N + col] = f2bf(v);
        }
  } else {
    float* C = (float*)Cout;
#pragma unroll
    for (int i = 0; i < 8; ++i)
#pragma unroll
      for (int j = 0; j < 4; ++j)
#pragma unroll
        for (int jj = 0; jj < 4; ++jj) {
          const long row = r0 + i * 16 + cr + jj;
          const long col = c0 + j * 16 + cc;
          C[row * N + col] = acc[i][j][jj] + bias[col] + bf2f(res[row * N + col]);
        }
  }
}

// ---------------- softmax over rows of S (in-place, bf16) ----------------

__global__ __launch_bounds__(256) void k_softmax(unsigned short* __restrict__ S) {
  __shared__ float red[8];
  const long base = (long)blockIdx.x * UDIM;
  const int t = threadIdx.x;
  ushort8 raw = *(const ushort8*)(S + base + t * 8);
  float v[8];
  float mx = -3.0e38f;
#pragma unroll
  for (int j = 0; j < 8; ++j) {
    v[j] = bf2f(raw[j]);
    mx = fmaxf(mx, v[j]);
  }
#pragma unroll
  for (int m = 32; m >= 1; m >>= 1) mx = fmaxf(mx, __shfl_xor(mx, m));
  const int wv = t >> 6;
  if ((t & 63) == 0) red[wv] = mx;
  __syncthreads();
  mx = fmaxf(fmaxf(red[0], red[1]), fmaxf(red[2], red[3]));
  float s = 0.f;
#pragma unroll
  for (int j = 0; j < 8; ++j) {
    v[j] = __expf(v[j] - mx);
    s += v[j];
  }
#pragma unroll
  for (int m = 32; m >= 1; m >>= 1) s += __shfl_xor(s, m);
  if ((t & 63) == 0) red[4 + wv] = s;
  __syncthreads();
  s = red[4] + red[5] + red[6] + red[7];
  const float rs = 1.f / s;
  ushort8 o;
#pragma unroll
  for (int j = 0; j < 8; ++j) o[j] = f2bf(v[j] * rs);
  *(ushort8*)(S + base + t * 8) = o;
}

// ---------------- X = LN(Q + V_att) -> bf16 ----------------

__global__ __launch_bounds__(256) void k_addln_bf16(
    const float* __restrict__ Q, const unsigned short* __restrict__ Va,
    unsigned short* __restrict__ X, const float* __restrict__ gamma,
    const float* __restrict__ beta) {
  __shared__ float red[8];
  const long base = (long)blockIdx.x * DDIM;
  const int t = threadIdx.x;
  float4v q = *(const float4v*)(Q + base + t * 4);
  ushort4v a = *(const ushort4v*)(Va + base + t * 4);
  float x[4];
  float s = 0.f, ss = 0.f;
#pragma unroll
  for (int j = 0; j < 4; ++j) {
    x[j] = q[j] + bf2f(a[j]);
    s += x[j];
    ss += x[j] * x[j];
  }
#pragma unroll
  for (int m = 32; m >= 1; m >>= 1) {
    s += __shfl_xor(s, m);
    ss += __shfl_xor(ss, m);
  }
  const int wv = t >> 6;
  if ((t & 63) == 0) {
    red[wv] = s;
    red[4 + wv] = ss;
  }
  __syncthreads();
  s = red[0] + red[1] + red[2] + red[3];
  ss = red[4] + red[5] + red[6] + red[7];
  const float mu = s * (1.f / DDIM);
  const float var = ss * (1.f / DDIM) - mu * mu;
  const float rstd = rsqrtf(var + 1e-6f);
  ushort4v o;
#pragma unroll
  for (int j = 0; j < 4; ++j) {
    const int c = t * 4 + j;
    o[j] = f2bf(gamma[c] * ((x[j] - mu) * rstd) + beta[c]);
  }
  *(ushort4v*)(X + base + t * 4) = o;
}

// ---------------- in-place LN on fp32 rows ----------------

__global__ __launch_bounds__(256) void k_ln_inplace(float* __restrict__ Y,
                                                    const float* __restrict__ gamma,
                                                    const float* __restrict__ beta) {
  __shared__ float red[8];
  const long base = (long)blockIdx.x * DDIM;
  const int t = threadIdx.x;
  float4v y = *(const float4v*)(Y + base + t * 4);
  float s = 0.f, ss = 0.f;
#pragma unroll
  for (int j = 0; j < 4; ++j) {
    s += y[j];
    ss += y[j] * y[j];
  }
#pragma unroll
  for (int m = 32; m >= 1; m >>= 1) {
    s += __shfl_xor(s, m);
    ss += __shfl_xor(ss, m);
  }
  const int wv = t >> 6;
  if ((t & 63) == 0) {
    red[wv] = s;
    red[4 + wv] = ss;
  }
  __syncthreads();
  s = red[0] + red[1] + red[2] + red[3];
  ss = red[4] + red[5] + red[6] + red[7];
  const float mu = s * (1.f / DDIM);
  const float var = ss * (1.f / DDIM) - mu * mu;
  const float rstd = rsqrtf(var + 1e-6f);
  float4v o;
#pragma unroll
  for (int j = 0; j < 4; ++j) {
    const int c = t * 4 + j;
    o[j] = gamma[c] * ((y[j] - mu) * rstd) + beta[c];
  }
  *(float4v*)(Y + base + t * 4) = o;
}

// ---------------- launch ----------------

extern "C" void kernel_launch(void* const* d_in, const int* in_sizes, int n_in,
                              void* d_out, int out_size, void* d_ws, size_t ws_size,
                              hipStream_t stream) {
  const float* Q = (const float*)d_in[0];
  const float* Kin = (const float*)d_in[1];
  const float* V = (const float*)d_in[2];
  const float* W1 = (const float*)d_in[3];
  const float* b1 = (const float*)d_in[4];
  const float* W2 = (const float*)d_in[5];
  const float* b2 = (const float*)d_in[6];
  const float* gamma = (const float*)d_in[7];
  const float* beta = (const float*)d_in[8];
  float* out = (float*)d_out;

  const long nQ = (long)BATCH * RDIM * DDIM;
  const long nK = (long)BATCH * UDIM * DDIM;
  const long nS = (long)BATCH * RDIM * UDIM;

  char* w = (char*)d_ws;
  unsigned short* Qb = (unsigned short*)w;  w += nQ * 2;
  unsigned short* Kb = (unsigned short*)w;  w += nK * 2;
  unsigned short* Vt = (unsigned short*)w;  w += nK * 2;
  unsigned short* S  = (unsigned short*)w;  w += nS * 2;
  unsigned short* X  = (unsigned short*)w;  w += nQ * 2;
  unsigned short* W1t = (unsigned short*)w; w += (long)DDIM * DDIM * 2;
  unsigned short* W2t = (unsigned short*)w; w += (long)DDIM * DDIM * 2;
  unsigned short* Va = Qb;  // reuse: Qb dead after S-gemm
  unsigned short* H  = S;   // reuse: S dead after PV-gemm

  const float scale = 1.0f / sqrtf(1024.0f + 1e-8f);

  k_conv_bf16<<<nQ / 2048, 256, 0, stream>>>(Q, Qb, scale);
  k_conv_bf16<<<nK / 2048, 256, 0, stream>>>(Kin, Kb, 1.0f);
  k_transpose_bf16<<<dim3(UDIM / 64, DDIM / 64, BATCH), dim3(64, 4), 0, stream>>>(
      V, Vt, UDIM, DDIM, (long)UDIM * DDIM, (long)UDIM * DDIM);
  k_transpose_bf16<<<dim3(DDIM / 64, DDIM / 64, 1), dim3(64, 4), 0, stream>>>(
      W1, W1t, DDIM, DDIM, 0, 0);
  k_transpose_bf16<<<dim3(DDIM / 64, DDIM / 64, 1), dim3(64, 4), 0, stream>>>(
      W2, W2t, DDIM, DDIM, 0, 0);

  // S = (Q/scale) @ K^T   [per batch 2048x2048, K=1024]
  gemm_bt<0><<<dim3(RDIM / 256, UDIM / 256, BATCH), 512, 0, stream>>>(
      Qb, Kb, S, UDIM, DDIM, (long)RDIM * DDIM, (long)UDIM * DDIM, (long)RDIM * UDIM,
      nullptr, nullptr);
  k_softmax<<<BATCH * RDIM, 256, 0, stream>>>(S);
  // V_att = P @ V   [per batch 2048x1024, K=2048]
  gemm_bt<0><<<dim3(RDIM / 256, DDIM / 256, BATCH), 512, 0, stream>>>(
      S, Vt, Va, DDIM, UDIM, (long)RDIM * UDIM, (long)DDIM * UDIM, (long)RDIM * DDIM,
      nullptr, nullptr);
  // X = LN(Q + V_att)
  k_addln_bf16<<<BATCH * RDIM, 256, 0, stream>>>(Q, Va, X, gamma, beta);
  // H = relu(X @ W1 + b1)   [32768x1024, K=1024]
  gemm_bt<1><<<dim3(BATCH * RDIM / 256, DDIM / 256, 1), 512, 0, stream>>>(
      X, W1t, H, DDIM, DDIM, 0, 0, 0, b1, nullptr);
  // out = H @ W2 + b2 + X  (pre-LN, fp32)
  gemm_bt<2><<<dim3(BATCH * RDIM / 256, DDIM / 256, 1), 512, 0, stream>>>(
      H, W2t, out, DDIM, DDIM, 0, 0, 0, b2, X);
  // out = LN(out)  in-place
  k_ln_inplace<<<BATCH * RDIM, 256, 0, stream>>>(out, gamma, beta);
}

// Round 6
// 665.597 us; speedup vs baseline: 1.0375x; 1.0375x over previous
//
#include <hip/hip_runtime.h>
#include <math.h>
#include <stdint.h>

#define BATCH 16
#define RDIM 2048
#define UDIM 2048
#define DDIM 1024

typedef __attribute__((ext_vector_type(8))) short short8;
typedef __attribute__((ext_vector_type(4))) float f32x4;
typedef __attribute__((ext_vector_type(8))) unsigned short ushort8;
typedef __attribute__((ext_vector_type(4))) unsigned short ushort4v;
typedef __attribute__((ext_vector_type(4))) float float4v;

__device__ __forceinline__ float bf2f(unsigned short u) {
  unsigned int x = ((unsigned int)u) << 16;
  return __builtin_bit_cast(float, x);
}
__device__ __forceinline__ unsigned short f2bf(float f) {
  unsigned int x = __builtin_bit_cast(unsigned int, f);
  unsigned int r = (x + 0x7fffu + ((x >> 16) & 1u)) >> 16;
  return (unsigned short)r;
}

__device__ __forceinline__ void gload_lds16(const void* g, void* l) {
  __builtin_amdgcn_global_load_lds(
      (const __attribute__((address_space(1))) void*)(uintptr_t)g,
      (__attribute__((address_space(3))) void*)(uint32_t)(uintptr_t)l,
      16, 0, 0);
}

#define FENCE() __builtin_amdgcn_sched_barrier(0)
#define BAR() __builtin_amdgcn_s_barrier()
#define LGKM0() asm volatile("s_waitcnt lgkmcnt(0)" ::: "memory")
#define LGKM4() asm volatile("s_waitcnt lgkmcnt(4)" ::: "memory")
#define LGKM8() asm volatile("s_waitcnt lgkmcnt(8)" ::: "memory")
#define VMCNT0() asm volatile("s_waitcnt vmcnt(0)" ::: "memory")

// ---------------- conversions ----------------

__global__ __launch_bounds__(256) void k_conv_bf16(const float* __restrict__ in,
                                                   unsigned short* __restrict__ out,
                                                   float scale) {
  const long i = ((long)blockIdx.x * 256 + threadIdx.x) * 8;
  float4v a = *(const float4v*)(in + i);
  float4v b = *(const float4v*)(in + i + 4);
  ushort8 o;
#pragma unroll
  for (int j = 0; j < 4; ++j) o[j] = f2bf(a[j] * scale);
#pragma unroll
  for (int j = 0; j < 4; ++j) o[4 + j] = f2bf(b[j] * scale);
  *(ushort8*)(out + i) = o;
}

// out[c*rows + r] = bf16(in[r*cols + c])
__global__ void k_transpose_bf16(const float* __restrict__ in,
                                 unsigned short* __restrict__ out,
                                 int rows, int cols, long sIn, long sOut) {
  __shared__ unsigned short tile[64][65];
  const long bz = blockIdx.z;
  in += bz * sIn;
  out += bz * sOut;
  const int r0 = blockIdx.x * 64;
  const int c0 = blockIdx.y * 64;
  const int tx = threadIdx.x;  // 64
  const int ty = threadIdx.y;  // 4
#pragma unroll
  for (int i = 0; i < 16; ++i) {
    const int r = ty + i * 4;
    tile[r][tx] = f2bf(in[(long)(r0 + r) * cols + c0 + tx]);
  }
  __syncthreads();
#pragma unroll
  for (int i = 0; i < 16; ++i) {
    const int r = ty + i * 4;
    out[(long)(c0 + r) * rows + r0 + tx] = tile[tx][r];
  }
}

// ---------------- GEMM: C[M,N] = A[M,K] * B[N,K]^T, bf16 in, fp32 acc -------
// 256x256 tile, BK=64 (2 k-halves), 512 threads = 8 waves (2Mx4N).
// LDS [buf][A,B][ks][256 rows x 32 elem] = 8 x 16 KiB slots, 64-B rows.
// T2 swizzle: phys 16B-slot = logicalSlot ^ ((row>>1)&3) -> conflict-free
// ds_read_b128; staging keeps LDS dest linear and pre-applies the inverse
// permutation on the global source column (both-sides involution; verified
// 0 bank conflicts in r4/r5).
// NEW (r6): decoupled pipeline, ONE barrier per K-tile.
//   ph0: issue reads q0(A-ks0 m0-3, B-ks0) + q1(A-ks0 m4-7); stage A(t+1);
//        lgkm(4) -> q0 landed, q1 in flight; 16 MFMA q0
//   ph1: issue q2(A-ks1 m0-3, B-ks1); stage B(t+1); lgkm(8) -> q1; MFMA q1
//   ph2: issue q3(A-ks1 m4-7); lgkm(4) -> q2; MFMA q2
//   ph3: lgkm(0) -> q3; MFMA q3; vmcnt(0); BAR
// No intra-tile barriers: LDS content for tile t is immutable (staged before
// the boundary BAR) and stages write the other buffer, so wave drift is safe
// and overlaps one wave's ds_reads with another's MFMA. The counted lgkm
// leaves the next quadrant's reads draining BEHIND the current MFMA cluster.
// vmcnt(0) at the boundary drains this tile's 8 stage-loads (issued ph0/ph1,
// >=2 phases of lead > HBM latency); WAR safe since all reads completed
// (lgkm(0)) before BAR and writes after BAR target the other buffer.
// T1: bijective XCD remap, y-fastest decode for panel reuse in per-XCD L2.

template <int EPI>
__global__ __launch_bounds__(512, 2) void gemm_bt(
    const unsigned short* __restrict__ A, const unsigned short* __restrict__ B,
    void* __restrict__ Cout, int N, int K, long sA, long sB, long sC,
    const float* __restrict__ bias, const unsigned short* __restrict__ res) {
  __shared__ __align__(128) unsigned short lds[2][2][2][256 * 32];

  // ---- T1: XCD-aware bijective remap (all grids are multiples of 8) ----
  int lin = blockIdx.x + gridDim.x * (blockIdx.y + gridDim.y * blockIdx.z);
  lin = (lin & 7) * ((gridDim.x * gridDim.y * gridDim.z) >> 3) + (lin >> 3);
  const int by = lin % gridDim.y;       // y-fastest: share A-panel in L2
  int rest = lin / gridDim.y;
  const int bx = rest % gridDim.x;
  const int bz = rest / gridDim.x;

  const unsigned short* Ab = A + (long)bz * sA;
  const unsigned short* Bb = B + (long)bz * sB;

  const int tid = threadIdx.x;
  const int w = tid >> 6;
  const int lane = tid & 63;
  const int wm = w >> 2;
  const int wn = w & 3;
  const long rowBase = (long)bx * 256;
  const long colBase = (long)by * 256;

  // staging: lane l writes LDS linear byte w*1024 + q*8192 + l*16
  //   -> row = w*16 + q*128 + (l>>2), physSlot = l&3
  //   -> fetch logical slot (l&3) ^ ((row>>1)&3) = (l&3) ^ ((l>>3)&3)
  const int stRow = w * 16 + (lane >> 2);
  const int stKc = ((lane & 3) ^ ((lane >> 3) & 3)) << 3;  // elements
  const unsigned short* gA = Ab + (rowBase + stRow) * (long)K + stKc;
  const unsigned short* gB = Bb + (colBase + stRow) * (long)K + stKc;
  const long qStep = (long)128 * K;
  char* ldsB = (char*)&lds[0][0][0][0];
  const int dOff = w * 1024;

  auto STAGE = [&](int buf, int op, int ks, int kadd) {
    const unsigned short* g = (op == 0 ? gA : gB) + kadd;
    char* d = ldsB + ((buf * 4 + op * 2 + ks) << 14) + dOff;
    gload_lds16(g, d);
    gload_lds16(g + qStep, d + 8192);
  };

  // fragment reads: row = base16 + laneM, phys slot = laneQ ^ ((laneM>>1)&3)
  const int laneM = lane & 15;
  const int laneQ = lane >> 4;
  const int swz = (laneQ ^ ((laneM >> 1) & 3)) << 4;
  const int rdA = (wm * 128 + laneM) * 64 + swz;
  const int rdB = (wn * 64 + laneM) * 64 + swz;

  f32x4 acc[8][4] = {};
  const int NT = K >> 6;
  const int NTm1 = NT - 1;

  // prologue: stage tile 0 into buf 0 (8 loads), drain, sync
  STAGE(0, 0, 0, 0);
  STAGE(0, 0, 1, 32);
  STAGE(0, 1, 0, 0);
  STAGE(0, 1, 1, 32);
  VMCNT0();
  BAR();
  FENCE();

  for (int t = 0; t < NT; ++t) {
    const int cur = t & 1;
    const int nxt = cur ^ 1;
    const int sA0 = (cur * 4 + 0) << 14;
    const int sA1 = (cur * 4 + 1) << 14;
    const int sB0 = (cur * 4 + 2) << 14;
    const int sB1 = (cur * 4 + 3) << 14;
    const int tn = (t + 1 <= NTm1 ? t + 1 : NTm1);
    const int ka = tn * 64;

    short8 a0[4], a1[4], a2[4], a3[4], b0[4], b1[4];

    // ---- ph0: issue q0 (a0,b0) then q1 (a1); stage A(t+1); wait q0 ----
#pragma unroll
    for (int m = 0; m < 4; ++m)
      a0[m] = *(const short8*)(ldsB + sA0 + rdA + m * 1024);
#pragma unroll
    for (int n = 0; n < 4; ++n)
      b0[n] = *(const short8*)(ldsB + sB0 + rdB + n * 1024);
    FENCE();  // pin q0 reads as oldest in the lgkm FIFO
#pragma unroll
    for (int m = 0; m < 4; ++m)
      a1[m] = *(const short8*)(ldsB + sA0 + rdA + (4 + m) * 1024);
    STAGE(nxt, 0, 0, ka);
    STAGE(nxt, 0, 1, ka + 32);
    LGKM4();  // q0 landed; q1 drains behind MFMA
    FENCE();
    __builtin_amdgcn_s_setprio(1);
#pragma unroll
    for (int m = 0; m < 4; ++m)
#pragma unroll
      for (int n = 0; n < 4; ++n)
        acc[m][n] = __builtin_amdgcn_mfma_f32_16x16x32_bf16(a0[m], b0[n],
                                                            acc[m][n], 0, 0, 0);
    __builtin_amdgcn_s_setprio(0);

    // ---- ph1: issue q2 (a2,b1); stage B(t+1); wait q1 ----
#pragma unroll
    for (int m = 0; m < 4; ++m)
      a2[m] = *(const short8*)(ldsB + sA1 + rdA + m * 1024);
#pragma unroll
    for (int n = 0; n < 4; ++n)
      b1[n] = *(const short8*)(ldsB + sB1 + rdB + n * 1024);
    STAGE(nxt, 1, 0, ka);
    STAGE(nxt, 1, 1, ka + 32);
    LGKM8();  // q1 landed; q2 drains behind MFMA
    FENCE();
    __builtin_amdgcn_s_setprio(1);
#pragma unroll
    for (int m = 0; m < 4; ++m)
#pragma unroll
      for (int n = 0; n < 4; ++n)
        acc[4 + m][n] = __builtin_amdgcn_mfma_f32_16x16x32_bf16(a1[m], b0[n],
                                                                acc[4 + m][n], 0, 0, 0);
    __builtin_amdgcn_s_setprio(0);

    // ---- ph2: issue q3 (a3); wait q2 ----
#pragma unroll
    for (int m = 0; m < 4; ++m)
      a3[m] = *(const short8*)(ldsB + sA1 + rdA + (4 + m) * 1024);
    LGKM4();  // q2 landed; q3 drains behind MFMA
    FENCE();
    __builtin_amdgcn_s_setprio(1);
#pragma unroll
    for (int m = 0; m < 4; ++m)
#pragma unroll
      for (int n = 0; n < 4; ++n)
        acc[m][n] = __builtin_amdgcn_mfma_f32_16x16x32_bf16(a2[m], b1[n],
                                                            acc[m][n], 0, 0, 0);
    __builtin_amdgcn_s_setprio(0);

    // ---- ph3: wait q3; MFMA; K-tile boundary sync ----
    LGKM0();  // all reads of tile t complete (also WAR guard for BAR)
    FENCE();
    __builtin_amdgcn_s_setprio(1);
#pragma unroll
    for (int m = 0; m < 4; ++m)
#pragma unroll
      for (int n = 0; n < 4; ++n)
        acc[4 + m][n] = __builtin_amdgcn_mfma_f32_16x16x32_bf16(a3[m], b1[n],
                                                                acc[4 + m][n], 0, 0, 0);
    __builtin_amdgcn_s_setprio(0);
    FENCE();
    VMCNT0();  // tile t+1 fully staged (8 loads, issued ph0/ph1: ~2-phase lead)
    BAR();
    FENCE();
  }

  const long r0 = rowBase + wm * 128;
  const long c0 = colBase + wn * 64;
  const int cr = (lane >> 4) << 2;
  const int cc = lane & 15;

  if constexpr (EPI == 0) {
    unsigned short* C = (unsigned short*)Cout + (long)bz * sC;
#pragma unroll
    for (int i = 0; i < 8; ++i)
#pragma unroll
      for (int j = 0; j < 4; ++j)
#pragma unroll
        for (int jj = 0; jj < 4; ++jj)
          C[(r0 + i * 16 + cr + jj) * N + (c0 + j * 16 + cc)] = f2bf(acc[i][j][jj]);
  } else if constexpr (EPI == 1) {
    unsigned short* C = (unsigned short*)Cout;
#pragma unroll
    for (int i = 0; i < 8; ++i)
#pragma unroll
      for (int j = 0; j < 4; ++j)
#pragma unroll
        for (int jj = 0; jj < 4; ++jj) {
          const long col = c0 + j * 16 + cc;
          float v = acc[i][j][jj] + bias[col];
          v = fmaxf(v, 0.f);
          C[(r0 + i * 16 + cr + jj) * N + col] = f2bf(v);
        }
  } else {
    float* C = (float*)Cout;
#pragma unroll
    for (int i = 0; i < 8; ++i)
#pragma unroll
      for (int j = 0; j < 4; ++j)
#pragma unroll
        for (int jj = 0; jj < 4; ++jj) {
          const long row = r0 + i * 16 + cr + jj;
          const long col = c0 + j * 16 + cc;
          C[row * N + col] = acc[i][j][jj] + bias[col] + bf2f(res[row * N + col]);
        }
  }
}

// ---------------- softmax over rows of S (in-place, bf16) ----------------

__global__ __launch_bounds__(256) void k_softmax(unsigned short* __restrict__ S) {
  __shared__ float red[8];
  const long base = (long)blockIdx.x * UDIM;
  const int t = threadIdx.x;
  ushort8 raw = *(const ushort8*)(S + base + t * 8);
  float v[8];
  float mx = -3.0e38f;
#pragma unroll
  for (int j = 0; j < 8; ++j) {
    v[j] = bf2f(raw[j]);
    mx = fmaxf(mx, v[j]);
  }
#pragma unroll
  for (int m = 32; m >= 1; m >>= 1) mx = fmaxf(mx, __shfl_xor(mx, m));
  const int wv = t >> 6;
  if ((t & 63) == 0) red[wv] = mx;
  __syncthreads();
  mx = fmaxf(fmaxf(red[0], red[1]), fmaxf(red[2], red[3]));
  float s = 0.f;
#pragma unroll
  for (int j = 0; j < 8; ++j) {
    v[j] = __expf(v[j] - mx);
    s += v[j];
  }
#pragma unroll
  for (int m = 32; m >= 1; m >>= 1) s += __shfl_xor(s, m);
  if ((t & 63) == 0) red[4 + wv] = s;
  __syncthreads();
  s = red[4] + red[5] + red[6] + red[7];
  const float rs = 1.f / s;
  ushort8 o;
#pragma unroll
  for (int j = 0; j < 8; ++j) o[j] = f2bf(v[j] * rs);
  *(ushort8*)(S + base + t * 8) = o;
}

// ---------------- X = LN(Q + V_att) -> bf16 ----------------

__global__ __launch_bounds__(256) void k_addln_bf16(
    const float* __restrict__ Q, const unsigned short* __restrict__ Va,
    unsigned short* __restrict__ X, const float* __restrict__ gamma,
    const float* __restrict__ beta) {
  __shared__ float red[8];
  const long base = (long)blockIdx.x * DDIM;
  const int t = threadIdx.x;
  float4v q = *(const float4v*)(Q + base + t * 4);
  ushort4v a = *(const ushort4v*)(Va + base + t * 4);
  float x[4];
  float s = 0.f, ss = 0.f;
#pragma unroll
  for (int j = 0; j < 4; ++j) {
    x[j] = q[j] + bf2f(a[j]);
    s += x[j];
    ss += x[j] * x[j];
  }
#pragma unroll
  for (int m = 32; m >= 1; m >>= 1) {
    s += __shfl_xor(s, m);
    ss += __shfl_xor(ss, m);
  }
  const int wv = t >> 6;
  if ((t & 63) == 0) {
    red[wv] = s;
    red[4 + wv] = ss;
  }
  __syncthreads();
  s = red[0] + red[1] + red[2] + red[3];
  ss = red[4] + red[5] + red[6] + red[7];
  const float mu = s * (1.f / DDIM);
  const float var = ss * (1.f / DDIM) - mu * mu;
  const float rstd = rsqrtf(var + 1e-6f);
  ushort4v o;
#pragma unroll
  for (int j = 0; j < 4; ++j) {
    const int c = t * 4 + j;
    o[j] = f2bf(gamma[c] * ((x[j] - mu) * rstd) + beta[c]);
  }
  *(ushort4v*)(X + base + t * 4) = o;
}

// ---------------- in-place LN on fp32 rows ----------------

__global__ __launch_bounds__(256) void k_ln_inplace(float* __restrict__ Y,
                                                    const float* __restrict__ gamma,
                                                    const float* __restrict__ beta) {
  __shared__ float red[8];
  const long base = (long)blockIdx.x * DDIM;
  const int t = threadIdx.x;
  float4v y = *(const float4v*)(Y + base + t * 4);
  float s = 0.f, ss = 0.f;
#pragma unroll
  for (int j = 0; j < 4; ++j) {
    s += y[j];
    ss += y[j] * y[j];
  }
#pragma unroll
  for (int m = 32; m >= 1; m >>= 1) {
    s += __shfl_xor(s, m);
    ss += __shfl_xor(ss, m);
  }
  const int wv = t >> 6;
  if ((t & 63) == 0) {
    red[wv] = s;
    red[4 + wv] = ss;
  }
  __syncthreads();
  s = red[0] + red[1] + red[2] + red[3];
  ss = red[4] + red[5] + red[6] + red[7];
  const float mu = s * (1.f / DDIM);
  const float var = ss * (1.f / DDIM) - mu * mu;
  const float rstd = rsqrtf(var + 1e-6f);
  float4v o;
#pragma unroll
  for (int j = 0; j < 4; ++j) {
    const int c = t * 4 + j;
    o[j] = gamma[c] * ((y[j] - mu) * rstd) + beta[c];
  }
  *(float4v*)(Y + base + t * 4) = o;
}

// ---------------- launch ----------------

extern "C" void kernel_launch(void* const* d_in, const int* in_sizes, int n_in,
                              void* d_out, int out_size, void* d_ws, size_t ws_size,
                              hipStream_t stream) {
  const float* Q = (const float*)d_in[0];
  const float* Kin = (const float*)d_in[1];
  const float* V = (const float*)d_in[2];
  const float* W1 = (const float*)d_in[3];
  const float* b1 = (const float*)d_in[4];
  const float* W2 = (const float*)d_in[5];
  const float* b2 = (const float*)d_in[6];
  const float* gamma = (const float*)d_in[7];
  const float* beta = (const float*)d_in[8];
  float* out = (float*)d_out;

  const long nQ = (long)BATCH * RDIM * DDIM;
  const long nK = (long)BATCH * UDIM * DDIM;
  const long nS = (long)BATCH * RDIM * UDIM;

  char* w = (char*)d_ws;
  unsigned short* Qb = (unsigned short*)w;  w += nQ * 2;
  unsigned short* Kb = (unsigned short*)w;  w += nK * 2;
  unsigned short* Vt = (unsigned short*)w;  w += nK * 2;
  unsigned short* S  = (unsigned short*)w;  w += nS * 2;
  unsigned short* X  = (unsigned short*)w;  w += nQ * 2;
  unsigned short* W1t = (unsigned short*)w; w += (long)DDIM * DDIM * 2;
  unsigned short* W2t = (unsigned short*)w; w += (long)DDIM * DDIM * 2;
  unsigned short* Va = Qb;  // reuse: Qb dead after S-gemm
  unsigned short* H  = S;   // reuse: S dead after PV-gemm

  const float scale = 1.0f / sqrtf(1024.0f + 1e-8f);

  k_conv_bf16<<<nQ / 2048, 256, 0, stream>>>(Q, Qb, scale);
  k_conv_bf16<<<nK / 2048, 256, 0, stream>>>(Kin, Kb, 1.0f);
  k_transpose_bf16<<<dim3(UDIM / 64, DDIM / 64, BATCH), dim3(64, 4), 0, stream>>>(
      V, Vt, UDIM, DDIM, (long)UDIM * DDIM, (long)UDIM * DDIM);
  k_transpose_bf16<<<dim3(DDIM / 64, DDIM / 64, 1), dim3(64, 4), 0, stream>>>(
      W1, W1t, DDIM, DDIM, 0, 0);
  k_transpose_bf16<<<dim3(DDIM / 64, DDIM / 64, 1), dim3(64, 4), 0, stream>>>(
      W2, W2t, DDIM, DDIM, 0, 0);

  // S = (Q/scale) @ K^T   [per batch 2048x2048, K=1024]
  gemm_bt<0><<<dim3(RDIM / 256, UDIM / 256, BATCH), 512, 0, stream>>>(
      Qb, Kb, S, UDIM, DDIM, (long)RDIM * DDIM, (long)UDIM * DDIM, (long)RDIM * UDIM,
      nullptr, nullptr);
  k_softmax<<<BATCH * RDIM, 256, 0, stream>>>(S);
  // V_att = P @ V   [per batch 2048x1024, K=2048]
  gemm_bt<0><<<dim3(RDIM / 256, DDIM / 256, BATCH), 512, 0, stream>>>(
      S, Vt, Va, DDIM, UDIM, (long)RDIM * UDIM, (long)DDIM * UDIM, (long)RDIM * DDIM,
      nullptr, nullptr);
  // X = LN(Q + V_att)
  k_addln_bf16<<<BATCH * RDIM, 256, 0, stream>>>(Q, Va, X, gamma, beta);
  // H = relu(X @ W1 + b1)   [32768x1024, K=1024]
  gemm_bt<1><<<dim3(BATCH * RDIM / 256, DDIM / 256, 1), 512, 0, stream>>>(
      X, W1t, H, DDIM, DDIM, 0, 0, 0, b1, nullptr);
  // out = H @ W2 + b2 + X  (pre-LN, fp32)
  gemm_bt<2><<<dim3(BATCH * RDIM / 256, DDIM / 256, 1), 512, 0, stream>>>(
      H, W2t, out, DDIM, DDIM, 0, 0, 0, b2, X);
  // out = LN(out)  in-place
  k_ln_inplace<<<BATCH * RDIM, 256, 0, stream>>>(out, gamma, beta);
}